// Round 1
// baseline (1184.861 us; speedup 1.0000x reference)
//
#include <hip/hip_runtime.h>
#include <stdint.h>

namespace {

constexpr int BROWS = 1024;   // batch
constexpr int NIT   = 50000;  // n_items
constexpr int NH1   = 600;
constexpr int NH2   = 200;
constexpr int KXP   = 50016;  // NIT padded to x32 (K of gemm1)
constexpr int N1P   = 640;    // NH1 padded to x128 (N of gemm1)
constexpr int NEP   = 50048;  // NIT padded to x128 (N of gemm4)
constexpr int KEP   = 608;    // NH1 padded to x32  (K of gemm4)
constexpr int SPLITS = 8;
constexpr int KI_TOTAL = KXP / 32;                        // 1563
constexpr int KI_PER   = (KI_TOTAL + SPLITS - 1) / SPLITS; // 196

typedef _Float16 f16x8 __attribute__((ext_vector_type(8)));
typedef _Float16 f16x4 __attribute__((ext_vector_type(4)));
typedef float    f32x4 __attribute__((ext_vector_type(4)));

__device__ __forceinline__ void gld16(const void* g, void* l) {
  // async global->LDS, 16B per lane; LDS dest must be uniform-base + lane*16
  __builtin_amdgcn_global_load_lds(
      (__attribute__((address_space(1))) void*)(void*)g,
      (__attribute__((address_space(3))) void*)l, 16, 0, 0);
}

// ---------------------------------------------------------------- norms of x
__global__ __launch_bounds__(256) void norm_rows_k(const float* __restrict__ x,
                                                   float* __restrict__ invnorm) {
  const int row = blockIdx.x;
  const float4* xr = (const float4*)(x + (size_t)row * NIT);
  float ss = 0.f;
  for (int i = threadIdx.x; i < NIT / 4; i += 256) {
    float4 v = xr[i];
    ss += v.x * v.x + v.y * v.y + v.z * v.z + v.w * v.w;
  }
  for (int o = 32; o > 0; o >>= 1) ss += __shfl_down(ss, o);
  __shared__ float red[4];
  if ((threadIdx.x & 63) == 0) red[threadIdx.x >> 6] = ss;
  __syncthreads();
  if (threadIdx.x == 0) {
    float s = red[0] + red[1] + red[2] + red[3];
    invnorm[row] = 1.0f / fmaxf(sqrtf(s), 1e-12f);
  }
}

// ------------------------------------------- W1 [K,N] -> W1T f16 [N1P][KXP]
__global__ __launch_bounds__(256) void transpose_w1_k(const float* __restrict__ W1,
                                                      _Float16* __restrict__ W1T) {
  __shared__ float tile[32][33];
  const int kb = blockIdx.x * 32;
  const int nb = blockIdx.y * 32;
  const int tx = threadIdx.x & 31;
  const int ty = threadIdx.x >> 5;  // 0..7
  for (int i = 0; i < 32; i += 8) {
    int k = kb + ty + i, n = nb + tx;
    tile[ty + i][tx] = (k < NIT && n < NH1) ? W1[(size_t)k * NH1 + n] : 0.f;
  }
  __syncthreads();
  for (int i = 0; i < 32; i += 8) {
    int n = nb + ty + i, k = kb + tx;
    W1T[(size_t)n * KXP + k] = (_Float16)tile[tx][ty + i];
  }
}

// ---------------------------- item_emb -> f16 [NEP][KEP] (+ fp32 row norms^2)
__global__ __launch_bounds__(256) void prep_emb_k(const float* __restrict__ emb,
                                                  _Float16* __restrict__ embb,
                                                  float* __restrict__ esq) {
  const int row = blockIdx.x * 4 + (threadIdx.x >> 6);
  const int lane = threadIdx.x & 63;
  const float* er = emb + (size_t)row * NH1;
  float ss = 0.f;
  #pragma unroll
  for (int j = 0; j < 10; ++j) {
    int idx = lane + 64 * j;
    float v = (row < NIT && idx < NH1) ? er[idx] : 0.f;
    ss += v * v;
    if (idx < KEP) embb[(size_t)row * KEP + idx] = (_Float16)v;
  }
  for (int o = 32; o > 0; o >>= 1) ss += __shfl_down(ss, o);
  if (lane == 0) esq[row] = ss;
}

// -------------------------------------------------- MFMA NT GEMM, 128x128x32
// MODE 0: C1-partial  = x(fp32, converted in staging) @ W1T^T, split-K slabs
// MODE 1: dist        = hsq[m] - 2*(h3 @ emb^T) + esq[n]  -> d_out
template <int MODE>
__global__ __launch_bounds__(256) void mfma_nt_k(
    const void* __restrict__ Av, const _Float16* __restrict__ Bg,
    float* __restrict__ Cout, const float* __restrict__ hsq,
    const float* __restrict__ esq) {
  __shared__ _Float16 As[128 * 32];
  __shared__ _Float16 Bs[128 * 32];

  const int t = threadIdx.x;
  const int n0 = blockIdx.x * 128;
  const int m0 = blockIdx.y * 128;

  int ki0, ki1, lda, ldb;
  if (MODE == 0) {
    ki0 = blockIdx.z * KI_PER;
    ki1 = (ki0 + KI_PER < KI_TOTAL) ? ki0 + KI_PER : KI_TOTAL;
    lda = NIT; ldb = KXP;
  } else {
    ki0 = 0; ki1 = KEP / 32; lda = KEP; ldb = KEP;
  }

  const int lane = t & 63;
  const int wid = t >> 6;
  const int wm = wid >> 1, wn = wid & 1;
  const int lrow = lane & 15, quad = lane >> 4;

  const f32x4 zero = {0.f, 0.f, 0.f, 0.f};
  f32x4 acc[4][4];
  #pragma unroll
  for (int i = 0; i < 4; ++i)
    #pragma unroll
    for (int j = 0; j < 4; ++j) acc[i][j] = zero;

  for (int ki = ki0; ki < ki1; ++ki) {
    const int k0 = ki * 32;
    // ---- stage A tile [128 rows][32 k] ----
    if (MODE == 0) {
      const float* A = (const float*)Av;
      #pragma unroll
      for (int j = 0; j < 4; ++j) {
        int g = j * 256 + t;     // float4-chunk id, 0..1023
        int row = g >> 3;        // 0..127
        int kq = (g & 7) * 4;    // 0..28
        float4 v = {0.f, 0.f, 0.f, 0.f};
        if (k0 + kq < NIT)
          v = *(const float4*)(A + (size_t)(m0 + row) * lda + (k0 + kq));
        f16x4 h;
        h.x = (_Float16)v.x; h.y = (_Float16)v.y;
        h.z = (_Float16)v.z; h.w = (_Float16)v.w;
        *(f16x4*)(&As[row * 32 + kq]) = h;
      }
    } else {
      const _Float16* A = (const _Float16*)Av;
      #pragma unroll
      for (int j = 0; j < 2; ++j) {
        int c = j * 256 + t;
        int row = c >> 2, kk = (c & 3) * 8;
        gld16(A + (size_t)(m0 + row) * lda + (k0 + kk), &As[c * 8]);
      }
    }
    // ---- stage B tile [128 n][32 k] ----
    #pragma unroll
    for (int j = 0; j < 2; ++j) {
      int c = j * 256 + t;
      int row = c >> 2, kk = (c & 3) * 8;
      gld16(Bg + (size_t)(n0 + row) * ldb + (k0 + kk), &Bs[c * 8]);
    }
    __syncthreads();

    f16x8 af[4], bfr[4];
    #pragma unroll
    for (int mi = 0; mi < 4; ++mi)
      af[mi] = *(const f16x8*)(&As[(wm * 64 + mi * 16 + lrow) * 32 + quad * 8]);
    #pragma unroll
    for (int ni = 0; ni < 4; ++ni)
      bfr[ni] = *(const f16x8*)(&Bs[(wn * 64 + ni * 16 + lrow) * 32 + quad * 8]);
    #pragma unroll
    for (int mi = 0; mi < 4; ++mi)
      #pragma unroll
      for (int ni = 0; ni < 4; ++ni)
        acc[mi][ni] = __builtin_amdgcn_mfma_f32_16x16x32_f16(af[mi], bfr[ni],
                                                             acc[mi][ni], 0, 0, 0);
    __syncthreads();
  }

  // ---- epilogue; C/D layout: col = lane&15, row = (lane>>4)*4 + reg ----
  if (MODE == 0) {
    float* Cs = Cout + (size_t)blockIdx.z * BROWS * N1P;
    #pragma unroll
    for (int mi = 0; mi < 4; ++mi)
      #pragma unroll
      for (int r = 0; r < 4; ++r) {
        int row = m0 + wm * 64 + mi * 16 + quad * 4 + r;
        #pragma unroll
        for (int ni = 0; ni < 4; ++ni) {
          int col = n0 + wn * 64 + ni * 16 + lrow;
          Cs[(size_t)row * N1P + col] = acc[mi][ni][r];
        }
      }
  } else {
    #pragma unroll
    for (int mi = 0; mi < 4; ++mi)
      #pragma unroll
      for (int r = 0; r < 4; ++r) {
        int row = m0 + wm * 64 + mi * 16 + quad * 4 + r;
        float hv = hsq[row];
        #pragma unroll
        for (int ni = 0; ni < 4; ++ni) {
          int col = n0 + wn * 64 + ni * 16 + lrow;
          if (col < NIT)
            Cout[(size_t)row * NIT + col] = hv - 2.f * acc[mi][ni][r] + esq[col];
        }
      }
  }
}

// ------------------------- sum split-K slabs, scale by invnorm, +b1, tanh
__global__ __launch_bounds__(256) void reduce_epi1_k(const float* __restrict__ C1p,
                                                     const float* __restrict__ invnorm,
                                                     const float* __restrict__ b1,
                                                     float* __restrict__ h1) {
  int idx = blockIdx.x * 256 + threadIdx.x;
  if (idx >= BROWS * NH1) return;
  int m = idx / NH1, n = idx - m * NH1;
  float s = 0.f;
  #pragma unroll
  for (int sp = 0; sp < SPLITS; ++sp)
    s += C1p[(size_t)sp * BROWS * N1P + (size_t)m * N1P + n];
  h1[idx] = tanhf(invnorm[m] * s + b1[n]);
}

// ------------------------------------------------ h2 = tanh(h1 @ W2 + b2)
__global__ __launch_bounds__(256) void gemm2_k(const float* __restrict__ h1,
                                               const float* __restrict__ W2,
                                               const float* __restrict__ b2,
                                               float* __restrict__ h2) {
  __shared__ float hs[8 * NH1];
  const int m0 = blockIdx.x * 8;
  const int t = threadIdx.x;
  for (int i = t; i < 8 * NH1; i += 256) hs[i] = h1[(size_t)m0 * NH1 + i];
  __syncthreads();
  if (t < NH2) {
    float acc[8];
    #pragma unroll
    for (int r = 0; r < 8; ++r) acc[r] = 0.f;
    for (int k = 0; k < NH1; ++k) {
      float w = W2[k * NH2 + t];
      #pragma unroll
      for (int r = 0; r < 8; ++r) acc[r] += hs[r * NH1 + k] * w;
    }
    float bb = b2[t];
    #pragma unroll
    for (int r = 0; r < 8; ++r) h2[(size_t)(m0 + r) * NH2 + t] = tanhf(acc[r] + bb);
  }
}

// --------------------- h3 = tanh(h2 @ W3 + b3) -> f16 [BROWS][KEP] + hsq
__global__ __launch_bounds__(256) void gemm3_k(const float* __restrict__ h2,
                                               const float* __restrict__ W3,
                                               const float* __restrict__ b3,
                                               _Float16* __restrict__ h3h,
                                               float* __restrict__ hsq) {
  __shared__ float hs[8 * NH2];
  __shared__ float red[8 * 256];
  const int m0 = blockIdx.x * 8;
  const int t = threadIdx.x;
  for (int i = t; i < 8 * NH2; i += 256) hs[i] = h2[(size_t)m0 * NH2 + i];
  __syncthreads();
  float ssq[8];
  #pragma unroll
  for (int r = 0; r < 8; ++r) ssq[r] = 0.f;
  for (int c = 0; c < 3; ++c) {
    int n = t + c * 256;
    if (n < NH1) {
      float acc[8];
      #pragma unroll
      for (int r = 0; r < 8; ++r) acc[r] = 0.f;
      for (int k = 0; k < NH2; ++k) {
        float w = W3[k * NH1 + n];
        #pragma unroll
        for (int r = 0; r < 8; ++r) acc[r] += hs[r * NH2 + k] * w;
      }
      float bb = b3[n];
      #pragma unroll
      for (int r = 0; r < 8; ++r) {
        float v = tanhf(acc[r] + bb);
        h3h[(size_t)(m0 + r) * KEP + n] = (_Float16)v;
        ssq[r] += v * v;
      }
    } else if (n < KEP) {
      #pragma unroll
      for (int r = 0; r < 8; ++r) h3h[(size_t)(m0 + r) * KEP + n] = (_Float16)0.f;
    }
  }
  #pragma unroll
  for (int r = 0; r < 8; ++r) red[r * 256 + t] = ssq[r];
  __syncthreads();
  if (t < 8) {
    float s = 0.f;
    for (int i = 0; i < 256; ++i) s += red[t * 256 + i];
    hsq[m0 + t] = s;
  }
}

}  // namespace

extern "C" void kernel_launch(void* const* d_in, const int* in_sizes, int n_in,
                              void* d_out, int out_size, void* d_ws, size_t ws_size,
                              hipStream_t stream) {
  const float* x   = (const float*)d_in[0];
  const float* W1  = (const float*)d_in[1];
  const float* b1  = (const float*)d_in[2];
  const float* W2  = (const float*)d_in[3];
  const float* b2  = (const float*)d_in[4];
  const float* W3  = (const float*)d_in[5];
  const float* b3  = (const float*)d_in[6];
  const float* emb = (const float*)d_in[7];
  float* out = (float*)d_out;

  char* ws = (char*)d_ws;
  // ws layout (all offsets 256B-aligned), peak ~85.6 MiB:
  const size_t oW1T = 0;                               // 64,020,480 B  (f16 [640][50016])
  const size_t oC1P = 64020480;                        // 20,971,520 B  (8 slabs [1024][640] f32)
  const size_t oINV = oC1P + 20971520;                 //      4,096 B
  const size_t oESQ = oINV + 4096;                     //    200,192 B
  const size_t oH1  = oESQ + 200192;                   //  2,457,600 B
  const size_t oH2  = oH1 + 2457600;                   //    819,200 B
  const size_t oH3  = oH2 + 819200;                    //  1,245,184 B
  const size_t oHSQ = oH3 + 1245184;                   //      4,096 B
  const size_t need = oHSQ + 4096;
  if (ws_size < need) return;  // ws too small -> fail visibly (poison output)

  _Float16* W1T   = (_Float16*)(ws + oW1T);
  float*    C1p   = (float*)(ws + oC1P);
  float*    invn  = (float*)(ws + oINV);
  float*    esq   = (float*)(ws + oESQ);
  float*    h1    = (float*)(ws + oH1);
  float*    h2    = (float*)(ws + oH2);
  _Float16* h3h   = (_Float16*)(ws + oH3);
  float*    hsq   = (float*)(ws + oHSQ);
  _Float16* embb  = (_Float16*)(ws + oW1T);  // aliases W1T (dead after gemm1)

  norm_rows_k<<<dim3(BROWS), dim3(256), 0, stream>>>(x, invn);
  transpose_w1_k<<<dim3(KXP / 32, N1P / 32), dim3(256), 0, stream>>>(W1, W1T);
  mfma_nt_k<0><<<dim3(N1P / 128, BROWS / 128, SPLITS), dim3(256), 0, stream>>>(
      (const void*)x, W1T, C1p, nullptr, nullptr);
  reduce_epi1_k<<<dim3((BROWS * NH1 + 255) / 256), dim3(256), 0, stream>>>(
      C1p, invn, b1, h1);
  prep_emb_k<<<dim3(NEP / 4), dim3(256), 0, stream>>>(emb, embb, esq);
  gemm2_k<<<dim3(BROWS / 8), dim3(256), 0, stream>>>(h1, W2, b2, h2);
  gemm3_k<<<dim3(BROWS / 8), dim3(256), 0, stream>>>(h2, W3, b3, h3h, hsq);
  mfma_nt_k<1><<<dim3(NEP / 128, BROWS / 128, 1), dim3(256), 0, stream>>>(
      (const void*)h3h, embb, out, hsq, esq);
}